// Round 1
// baseline (531.291 us; speedup 1.0000x reference)
//
#include <hip/hip_runtime.h>
#include <math.h>

#define NN 256
#define NPAIR 32640            // 256*255/2
#define NSEG 16
#define SEGLEN 2040            // NPAIR/NSEG
#define MAT (NN*NN)            // 65536 floats

// float offsets inside d_ws
#define CS_U 0
#define CS_V (2*NPAIR)                 // 65280
#define MATS0 131072                   // 32 leaf matrices (U:0..15, V:16..31)
#define MATS1 (MATS0 + 32*MAT)         // up to 16 matrices
#define VT_OFF (MATS1 + 16*MAT)
#define W_OFF (VT_OFF + MAT)

// ---------------- 1) cos/sin tables ----------------
__global__ __launch_bounds__(256) void k_sincos(const float* __restrict__ au,
                                                const float* __restrict__ av,
                                                float* __restrict__ ws) {
    int id = blockIdx.x * 256 + threadIdx.x;
    if (id < NPAIR) {
        float s, c;
        sincosf(au[id], &s, &c);
        ws[CS_U + 2*id]     = c;
        ws[CS_U + 2*id + 1] = s;
    } else if (id < 2*NPAIR) {
        int k = id - NPAIR;
        float s, c;
        sincosf(av[k], &s, &c);
        ws[CS_V + 2*k]     = c;
        ws[CS_V + 2*k + 1] = s;
    }
}

// ---------------- 2) segment partial products ----------------
// grid: 2 (mat) x 16 (segment) x 4 (64-column chunk) = 128 blocks, 64 threads.
// Each thread owns ONE column of the 256x256 partial product; rotations touch
// rows only, so threads are fully independent (single wave, no barriers).
__global__ __launch_bounds__(64) void k_build(const float* __restrict__ ws,
                                              float* __restrict__ mats) {
    int b = blockIdx.x;
    int matid = b >> 6;          // 0=U, 1=V
    int seg   = (b >> 2) & 15;
    int chunk = b & 3;
    int t = threadIdx.x;         // 0..63
    int col = chunk * 64 + t;

    __shared__ float M[NN * 64];
    for (int r = 0; r < NN; ++r) M[r*64 + t] = (r == col) ? 1.0f : 0.0f;

    const float2* cs = (const float2*)(ws + (matid ? CS_V : CS_U));
    int kbeg = seg * SEGLEN, kend = kbeg + SEGLEN;

    // locate (i,j) of lexicographic pair index kbeg
    int i = 0, acc = 0;
    while (acc + (NN - 1 - i) <= kbeg) { acc += NN - 1 - i; ++i; }
    int j = i + 1 + (kbeg - acc);

    for (int k = kbeg; k < kend; ++k) {
        float2 v = cs[k];                 // (cos, sin), wave-uniform
        float ri = M[i*64 + t];
        float rj = M[j*64 + t];
        M[i*64 + t] = v.x * ri - v.y * rj;
        M[j*64 + t] = v.y * ri + v.x * rj;
        if (++j == NN) { ++i; j = i + 1; }
    }

    float* out = mats + (matid * NSEG + seg) * MAT;
    for (int r = 0; r < NN; ++r) out[r*NN + col] = M[r*64 + t];
}

// ---------------- 3) tree fold: C = A @ B (256x256 f32) ----------------
// in : U-side mats [0..2*nOut), V-side mats [2*nOut..4*nOut)
// out: U-side [0..nOut), V-side [nOut..2*nOut)
// product order: A = later segment = in[2p+1], B = in[2p]  (U = P_last ... P_0)
__global__ __launch_bounds__(256) void k_treemm(const float* __restrict__ in,
                                                float* __restrict__ out, int nOut) {
    int b = blockIdx.x;
    int m    = b >> 4;           // product id, 0..2*nOut-1
    int tile = b & 15;           // 16-row tile
    int nIn  = nOut * 2;
    int side = m / nOut;
    int p    = m - side * nOut;
    const float* A = in + (side * nIn + 2*p + 1) * MAT;
    const float* B = in + (side * nIn + 2*p) * MAT;
    float* C = out + m * MAT;

    int c = threadIdx.x;         // output column
    int r0 = tile * 16;
    float acc[16];
#pragma unroll
    for (int r = 0; r < 16; ++r) acc[r] = 0.0f;

    for (int k4 = 0; k4 < 64; ++k4) {
        float4 a[16];            // wave-uniform -> scalar loads
#pragma unroll
        for (int r = 0; r < 16; ++r)
            a[r] = *(const float4*)(A + (r0 + r) * NN + k4 * 4);
#pragma unroll
        for (int kk = 0; kk < 4; ++kk) {
            float bb = B[(k4*4 + kk) * NN + c];
#pragma unroll
            for (int r = 0; r < 16; ++r)
                acc[r] = fmaf(((const float*)&a[r])[kk], bb, acc[r]);
        }
    }
#pragma unroll
    for (int r = 0; r < 16; ++r) C[(r0 + r) * NN + c] = acc[r];
}

// ---------------- 4) transpose V -> VT ----------------
__global__ __launch_bounds__(256) void k_transpose(const float* __restrict__ V,
                                                   float* __restrict__ VT) {
    __shared__ float tile[16][17];
    int b = blockIdx.x;
    int ko = b & 15, oo = b >> 4;
    int tx = threadIdx.x & 15, ty = threadIdx.x >> 4;
    tile[ty][tx] = V[(oo*16 + ty) * NN + ko*16 + tx];
    __syncthreads();
    VT[(ko*16 + ty) * NN + oo*16 + tx] = tile[tx][ty];
}

// ---------------- 5) W[i][o] = sum_k U[i][k] * S[k] * VT[k][o] ----------------
__global__ __launch_bounds__(256) void k_wmat(const float* __restrict__ U,
                                              const float* __restrict__ VT,
                                              const float* __restrict__ S,
                                              float* __restrict__ W) {
    int c = threadIdx.x;
    int r0 = blockIdx.x * 16;
    float acc[16];
#pragma unroll
    for (int r = 0; r < 16; ++r) acc[r] = 0.0f;

    for (int k4 = 0; k4 < 64; ++k4) {
        float4 a[16];
#pragma unroll
        for (int r = 0; r < 16; ++r)
            a[r] = *(const float4*)(U + (r0 + r) * NN + k4 * 4);
        float4 s4 = *(const float4*)(S + k4 * 4);   // uniform
#pragma unroll
        for (int kk = 0; kk < 4; ++kk) {
            float bb = VT[(k4*4 + kk) * NN + c] * ((const float*)&s4)[kk];
#pragma unroll
            for (int r = 0; r < 16; ++r)
                acc[r] = fmaf(((const float*)&a[r])[kk], bb, acc[r]);
        }
    }
#pragma unroll
    for (int r = 0; r < 16; ++r) W[(r0 + r) * NN + c] = acc[r];
}

// ---------------- 6) out = x @ W + bias (f32 vector GEMM) ----------------
#define BM 64
#define KT 32
#define XS_STRIDE 36   // 32 + 4 pad: rows 4 apart land on different banks
__global__ __launch_bounds__(256) void k_gemm(const float* __restrict__ x,
                                              const float* __restrict__ W,
                                              const float* __restrict__ bias,
                                              float* __restrict__ out) {
    int t  = threadIdx.x;
    int tx = t & 15, ty = t >> 4;
    long row0 = (long)blockIdx.x * BM;

    __shared__ float Xs[BM * XS_STRIDE];   // 9.2 KB
    __shared__ float Ws[KT * NN];          // 32.8 KB

    float acc[4][16];
#pragma unroll
    for (int rr = 0; rr < 4; ++rr)
#pragma unroll
        for (int cc = 0; cc < 16; ++cc) acc[rr][cc] = 0.0f;

    const float* xbase = x + row0 * NN;

    for (int k0 = 0; k0 < NN; k0 += KT) {
        __syncthreads();
        // stage x tile: 64 rows x 32 k = 512 float4
#pragma unroll
        for (int u = 0; u < 2; ++u) {
            int f4  = u * 256 + t;
            int row = f4 >> 3;
            int kk4 = f4 & 7;
            float4 v = *(const float4*)(xbase + row * NN + k0 + kk4 * 4);
            *(float4*)(&Xs[row * XS_STRIDE + kk4 * 4]) = v;
        }
        // stage W tile: 32 rows x 256 = 2048 float4
#pragma unroll
        for (int u = 0; u < 8; ++u) {
            int f4 = u * 256 + t;
            int kk = f4 >> 6;
            int c4 = f4 & 63;
            float4 v = *(const float4*)(W + (k0 + kk) * NN + c4 * 4);
            *(float4*)(&Ws[kk * NN + c4 * 4]) = v;
        }
        __syncthreads();

#pragma unroll 4
        for (int kk = 0; kk < KT; ++kk) {
            float a[4];
#pragma unroll
            for (int rr = 0; rr < 4; ++rr)
                a[rr] = Xs[(ty * 4 + rr) * XS_STRIDE + kk];
#pragma unroll
            for (int g = 0; g < 4; ++g) {
                float4 bv = *(const float4*)(&Ws[kk * NN + g * 64 + tx * 4]);
#pragma unroll
                for (int rr = 0; rr < 4; ++rr) {
                    acc[rr][g*4+0] = fmaf(a[rr], bv.x, acc[rr][g*4+0]);
                    acc[rr][g*4+1] = fmaf(a[rr], bv.y, acc[rr][g*4+1]);
                    acc[rr][g*4+2] = fmaf(a[rr], bv.z, acc[rr][g*4+2]);
                    acc[rr][g*4+3] = fmaf(a[rr], bv.w, acc[rr][g*4+3]);
                }
            }
        }
    }

#pragma unroll
    for (int g = 0; g < 4; ++g) {
        float4 bv = *(const float4*)(bias + g * 64 + tx * 4);
#pragma unroll
        for (int rr = 0; rr < 4; ++rr) {
            float4 o;
            o.x = acc[rr][g*4+0] + bv.x;
            o.y = acc[rr][g*4+1] + bv.y;
            o.z = acc[rr][g*4+2] + bv.z;
            o.w = acc[rr][g*4+3] + bv.w;
            *(float4*)(out + (row0 + ty*4 + rr) * NN + g * 64 + tx * 4) = o;
        }
    }
}

extern "C" void kernel_launch(void* const* d_in, const int* in_sizes, int n_in,
                              void* d_out, int out_size, void* d_ws, size_t ws_size,
                              hipStream_t stream) {
    const float* x    = (const float*)d_in[0];
    const float* Uw   = (const float*)d_in[1];
    const float* Vw   = (const float*)d_in[2];
    const float* Sw   = (const float*)d_in[3];
    const float* bias = (const float*)d_in[4];
    float* out = (float*)d_out;
    float* ws  = (float*)d_ws;

    // 1) angle tables
    k_sincos<<<(2*NPAIR + 255) / 256, 256, 0, stream>>>(Uw, Vw, ws);
    // 2) 16 segment partial products per matrix (parallel over segments+columns)
    k_build<<<128, 64, 0, stream>>>(ws, ws + MATS0);
    // 3) fold 16 -> 8 -> 4 -> 2 -> 1 per side (order-preserving tree)
    k_treemm<<<2*8*16, 256, 0, stream>>>(ws + MATS0, ws + MATS1, 8);
    k_treemm<<<2*4*16, 256, 0, stream>>>(ws + MATS1, ws + MATS0, 4);
    k_treemm<<<2*2*16, 256, 0, stream>>>(ws + MATS0, ws + MATS1, 2);
    k_treemm<<<2*1*16, 256, 0, stream>>>(ws + MATS1, ws + MATS0, 1);
    // 4) VT for coalesced access in W build
    k_transpose<<<256, 256, 0, stream>>>(ws + MATS0 + MAT, ws + VT_OFF);
    // 5) W = U * diag(S) * V^T
    k_wmat<<<16, 256, 0, stream>>>(ws + MATS0, ws + VT_OFF, Sw, ws + W_OFF);
    // 6) out = x @ W + bias
    k_gemm<<<131072 / BM, 256, 0, stream>>>(x, ws + W_OFF, bias, out);
}

// Round 2
// 387.462 us; speedup vs baseline: 1.3712x; 1.3712x over previous
//
#include <hip/hip_runtime.h>
#include <hip/hip_bf16.h>
#include <math.h>

#define NN 256
#define NPAIR 32640            // 256*255/2
#define NSEG 16
#define MAT (NN*NN)            // 65536 floats

// float offsets inside d_ws
#define CS_U 0
#define CS_V (2*NPAIR)                 // 65280
#define MATS0 131072                   // 32 leaf matrices (U:0..15, V:16..31)
#define MATS1 (MATS0 + 32*MAT)         // up to 16 matrices
#define WBT_OFF (MATS1 + 16*MAT)       // 65536 ushort (bf16 W^T) = 32768 floats

// sweep-group boundaries: group g = sweeps [BD[g], BD[g+1]), ~2040 rotations each
static __device__ const int BD[NSEG+1] =
    {0,9,17,26,35,44,54,64,75,87,100,113,128,145,166,192,255};

typedef __attribute__((ext_vector_type(8))) short short8;
typedef __attribute__((ext_vector_type(4))) float f32x4;

__device__ __forceinline__ short f2bf(float f) {
    __hip_bfloat16 h = __float2bfloat16(f);   // RTN-even
    return *reinterpret_cast<short*>(&h);
}

// ---------------- 1) cos/sin tables ----------------
__global__ __launch_bounds__(256) void k_sincos(const float* __restrict__ au,
                                                const float* __restrict__ av,
                                                float* __restrict__ ws) {
    int id = blockIdx.x * 256 + threadIdx.x;
    if (id < NPAIR) {
        float s, c;
        sincosf(au[id], &s, &c);
        ws[CS_U + 2*id]     = c;
        ws[CS_U + 2*id + 1] = s;
    } else if (id < 2*NPAIR) {
        int k = id - NPAIR;
        float s, c;
        sincosf(av[k], &s, &c);
        ws[CS_V + 2*k]     = c;
        ws[CS_V + 2*k + 1] = s;
    }
}

// ---------------- 2) segment partial products (register-ri, unroll-8) --------
// grid: 2 (mat) x 16 (sweep-group) x 4 (64-col chunk) = 128 blocks, 64 threads.
// Row i of the current sweep lives in a register; the 8 rj reads per unroll
// group are independent LDS loads -> pipelined, no serial LDS round trips.
__global__ __launch_bounds__(64) void k_build(const float* __restrict__ ws,
                                              float* __restrict__ mats) {
    int b = blockIdx.x;
    int matid = b >> 6;          // 0=U, 1=V
    int seg   = (b >> 2) & 15;
    int chunk = b & 3;
    int t = threadIdx.x;         // 0..63
    int col = chunk * 64 + t;

    __shared__ float M[NN * 64];
#pragma unroll 4
    for (int r = 0; r < NN; ++r) M[r*64 + t] = (r == col) ? 1.0f : 0.0f;

    const float* cs = ws + (matid ? CS_V : CS_U);
    int i0 = BD[seg], i1 = BD[seg+1];
    int k = 255*i0 - (i0*(i0-1))/2;      // rotations before sweep i0

    for (int i = i0; i < i1; ++i) {
        float ri = M[i*64 + t];
        int j = i + 1;
        for (; j + 8 <= 256; j += 8, k += 8) {
            const float* cp = cs + 2*k;
            float2 c0 = *(const float2*)(cp);
            float2 c1 = *(const float2*)(cp + 2);
            float2 c2 = *(const float2*)(cp + 4);
            float2 c3 = *(const float2*)(cp + 6);
            float2 c4 = *(const float2*)(cp + 8);
            float2 c5 = *(const float2*)(cp + 10);
            float2 c6 = *(const float2*)(cp + 12);
            float2 c7 = *(const float2*)(cp + 14);
            float* Mj = &M[j*64 + t];
            float rj0 = Mj[0];   float rj1 = Mj[64];  float rj2 = Mj[128];
            float rj3 = Mj[192]; float rj4 = Mj[256]; float rj5 = Mj[320];
            float rj6 = Mj[384]; float rj7 = Mj[448];
            float wv;
            wv = c0.y*ri + c0.x*rj0; ri = c0.x*ri - c0.y*rj0; Mj[0]   = wv;
            wv = c1.y*ri + c1.x*rj1; ri = c1.x*ri - c1.y*rj1; Mj[64]  = wv;
            wv = c2.y*ri + c2.x*rj2; ri = c2.x*ri - c2.y*rj2; Mj[128] = wv;
            wv = c3.y*ri + c3.x*rj3; ri = c3.x*ri - c3.y*rj3; Mj[192] = wv;
            wv = c4.y*ri + c4.x*rj4; ri = c4.x*ri - c4.y*rj4; Mj[256] = wv;
            wv = c5.y*ri + c5.x*rj5; ri = c5.x*ri - c5.y*rj5; Mj[320] = wv;
            wv = c6.y*ri + c6.x*rj6; ri = c6.x*ri - c6.y*rj6; Mj[384] = wv;
            wv = c7.y*ri + c7.x*rj7; ri = c7.x*ri - c7.y*rj7; Mj[448] = wv;
        }
        for (; j <= 255; ++j, ++k) {
            float2 cc = *(const float2*)(cs + 2*k);
            float rj = M[j*64 + t];
            float wv = cc.y*ri + cc.x*rj;
            ri = cc.x*ri - cc.y*rj;
            M[j*64 + t] = wv;
        }
        M[i*64 + t] = ri;
    }

    float* outp = mats + (matid * NSEG + seg) * MAT;
#pragma unroll 4
    for (int r = 0; r < NN; ++r) outp[r*NN + col] = M[r*64 + t];
}

// ---------------- 3) tree fold: C = A @ B (256x256 f32) ----------------
__global__ __launch_bounds__(256) void k_treemm(const float* __restrict__ in,
                                                float* __restrict__ out, int nOut) {
    int b = blockIdx.x;
    int m    = b >> 4;
    int tile = b & 15;
    int nIn  = nOut * 2;
    int side = m / nOut;
    int p    = m - side * nOut;
    const float* A = in + (side * nIn + 2*p + 1) * MAT;
    const float* B = in + (side * nIn + 2*p) * MAT;
    float* C = out + m * MAT;

    int c = threadIdx.x;
    int r0 = tile * 16;
    float acc[16];
#pragma unroll
    for (int r = 0; r < 16; ++r) acc[r] = 0.0f;

    for (int k4 = 0; k4 < 64; ++k4) {
        float4 a[16];
#pragma unroll
        for (int r = 0; r < 16; ++r)
            a[r] = *(const float4*)(A + (r0 + r) * NN + k4 * 4);
#pragma unroll
        for (int kk = 0; kk < 4; ++kk) {
            float bb = B[(k4*4 + kk) * NN + c];
#pragma unroll
            for (int r = 0; r < 16; ++r)
                acc[r] = fmaf(((const float*)&a[r])[kk], bb, acc[r]);
        }
    }
#pragma unroll
    for (int r = 0; r < 16; ++r) C[(r0 + r) * NN + c] = acc[r];
}

// ------- 4) Wbt[n][i] = bf16( sum_k U[i][k] * S[k] * V[n][k] ) -------
__global__ __launch_bounds__(256) void k_wmatT(const float* __restrict__ U,
                                               const float* __restrict__ V,
                                               const float* __restrict__ S,
                                               unsigned short* __restrict__ Wbt) {
    int c = threadIdx.x;             // i (in-feature)
    int n0 = blockIdx.x * 16;        // n (out-feature) tile
    float acc[16];
#pragma unroll
    for (int r = 0; r < 16; ++r) acc[r] = 0.0f;

    for (int k4 = 0; k4 < 64; ++k4) {
        float4 u4 = *(const float4*)(U + c * NN + k4 * 4);   // per-lane row of U
        float4 s4 = *(const float4*)(S + k4 * 4);            // uniform
        u4.x *= s4.x; u4.y *= s4.y; u4.z *= s4.z; u4.w *= s4.w;
#pragma unroll
        for (int r = 0; r < 16; ++r) {
            float4 v4 = *(const float4*)(V + (n0 + r) * NN + k4 * 4);  // uniform
            acc[r] += u4.x*v4.x + u4.y*v4.y + u4.z*v4.z + u4.w*v4.w;
        }
    }
#pragma unroll
    for (int r = 0; r < 16; ++r)
        Wbt[(n0 + r) * NN + c] = (unsigned short)f2bf(acc[r]);
}

// ---------------- 5) out = x @ W + bias : bf16 MFMA, W in VGPRs --------------
// 512 thr = 8 waves; wave w owns cols [32w, 32w+32). Full K=256 of its W slice
// lives in 64 VGPRs (16 B-fragments). Grid-strides over 16-row M-tiles.
// No LDS, no barriers; x read exactly once from HBM, W from L2.
__global__ __launch_bounds__(512, 4) void k_mm(const float* __restrict__ x,
                                               const unsigned short* __restrict__ Wbt,
                                               const float* __restrict__ bias,
                                               float* __restrict__ out) {
    int t = threadIdx.x;
    int w = t >> 6;          // wave 0..7
    int l = t & 63;
    int l15 = l & 15;
    int lg  = l >> 4;        // k-group 0..3
    int n0 = w * 32;

    // preload B-fragments: B[k][n], lane holds col n0+nt*16+l15, k = ks*32+lg*8+e
    short8 bfrag[2][8];
#pragma unroll
    for (int nt = 0; nt < 2; ++nt) {
        const unsigned short* wrow = Wbt + (n0 + nt*16 + l15) * NN + lg * 8;
#pragma unroll
        for (int ks = 0; ks < 8; ++ks)
            bfrag[nt][ks] = *(const short8*)(wrow + ks * 32);
    }
    float b0 = bias[n0 + l15];
    float b1 = bias[n0 + 16 + l15];

    for (int tile = blockIdx.x; tile < 8192; tile += gridDim.x) {
        const float* xp = x + ((long)tile * 16 + l15) * NN + lg * 8;
        f32x4 acc0 = {0.f, 0.f, 0.f, 0.f};
        f32x4 acc1 = {0.f, 0.f, 0.f, 0.f};
#pragma unroll
        for (int ks = 0; ks < 8; ++ks) {
            float4 a0 = *(const float4*)(xp + ks * 32);
            float4 a1 = *(const float4*)(xp + ks * 32 + 4);
            short8 af;
            af[0] = f2bf(a0.x); af[1] = f2bf(a0.y);
            af[2] = f2bf(a0.z); af[3] = f2bf(a0.w);
            af[4] = f2bf(a1.x); af[5] = f2bf(a1.y);
            af[6] = f2bf(a1.z); af[7] = f2bf(a1.w);
            acc0 = __builtin_amdgcn_mfma_f32_16x16x32_bf16(af, bfrag[0][ks], acc0, 0, 0, 0);
            acc1 = __builtin_amdgcn_mfma_f32_16x16x32_bf16(af, bfrag[1][ks], acc1, 0, 0, 0);
        }
        // D: col = lane&15, row = (lane>>4)*4 + reg  (m89-verified layout)
        float* op = out + ((long)tile * 16 + lg * 4) * NN + n0 + l15;
#pragma unroll
        for (int r = 0; r < 4; ++r) {
            op[r * NN]      = acc0[r] + b0;
            op[r * NN + 16] = acc1[r] + b1;
        }
    }
}

extern "C" void kernel_launch(void* const* d_in, const int* in_sizes, int n_in,
                              void* d_out, int out_size, void* d_ws, size_t ws_size,
                              hipStream_t stream) {
    const float* x    = (const float*)d_in[0];
    const float* Uw   = (const float*)d_in[1];
    const float* Vw   = (const float*)d_in[2];
    const float* Sw   = (const float*)d_in[3];
    const float* bias = (const float*)d_in[4];
    float* out = (float*)d_out;
    float* ws  = (float*)d_ws;

    // 1) angle tables (2*NPAIR = 65280 = 255*256)
    k_sincos<<<255, 256, 0, stream>>>(Uw, Vw, ws);
    // 2) 16 sweep-aligned segment partial products per matrix
    k_build<<<128, 64, 0, stream>>>(ws, ws + MATS0);
    // 3) fold 16 -> 8 -> 4 -> 2 -> 1 per side (order-preserving tree)
    k_treemm<<<2*8*16, 256, 0, stream>>>(ws + MATS0, ws + MATS1, 8);
    k_treemm<<<2*4*16, 256, 0, stream>>>(ws + MATS1, ws + MATS0, 4);
    k_treemm<<<2*2*16, 256, 0, stream>>>(ws + MATS0, ws + MATS1, 2);
    k_treemm<<<2*1*16, 256, 0, stream>>>(ws + MATS1, ws + MATS0, 1);
    // 4) Wbt = bf16( (U S V^T)^T )  -- direct, no transpose kernel needed
    k_wmatT<<<16, 256, 0, stream>>>(ws + MATS0, ws + MATS0 + MAT, Sw,
                                    (unsigned short*)(ws + WBT_OFF));
    // 5) out = x @ W + bias  (bf16 MFMA)
    k_mm<<<512, 512, 0, stream>>>(x, (unsigned short*)(ws + WBT_OFF), bias, out);
}